// Round 9
// baseline (409.626 us; speedup 1.0000x reference)
//
#include <hip/hip_runtime.h>

typedef unsigned int uint;
typedef unsigned short ushort;
typedef float f32x2 __attribute__((ext_vector_type(2)));

#define N_NODES 100000
#define N_EDGES 3200000
#define IN_CH 128
#define HID 64
#define N_GRAPHS 512
#define EPB 4096                                   // edges per block (binning)
#define NBLK ((N_EDGES + EPB - 1) / EPB)           // 782
#define NB 391                                     // buckets = dst>>8 (256 nodes each)
#define CAP 10240                                  // bucket capacity (mean 8192, 22 sigma)

// ---------------------------------------------------------------------------
// bf16 helpers: A and B matrices are packed bf16 (uint = 2 channels: 2j, 2j+1)
__device__ __forceinline__ uint f2bf1(float f) {
    union { float f; uint i; } v; v.f = f;
    return (v.i + 0x7fffu + ((v.i >> 16) & 1u)) >> 16;    // RNE
}
__device__ __forceinline__ uint pack2(float lo, float hi) {
    return f2bf1(lo) | (f2bf1(hi) << 16);
}
__device__ __forceinline__ float2 ub2(uint u) {
    union { uint i; float f; } a, b;
    a.i = u << 16; b.i = u & 0xffff0000u;
    return make_float2(a.f, b.f);
}
// unpack to ext-vector float2 (v_pk_add_f32-friendly accumulation)
__device__ __forceinline__ f32x2 up2(uint u) {
    union { uint i; float f; } lo, hi;
    lo.i = u << 16; hi.i = u & 0xffff0000u;
    f32x2 r; r.x = lo.f; r.y = hi.f;
    return r;
}

// ---------------------------------------------------------------------------
// Coalesced multisplit scatter (R5/R6-proven): histogram + global reservation,
// block-local scan -> LDS multisplit into bucket-contiguous runs -> coalesced
// flush (consecutive lanes, same bucket).
__global__ __launch_bounds__(256) void scatter_kernel(const int* __restrict__ src,
                                                      const int* __restrict__ dst,
                                                      int* __restrict__ bcnt,
                                                      uint* __restrict__ pairs) {
    __shared__ int h4[4 * NB];          // replicated histograms (6.3 KB)
    __shared__ int gbase[NB];           // b*CAP + start - loff (1.6 KB)
    __shared__ int cur[NB];             // local cursor, starts at loff (1.6 KB)
    __shared__ int scan[512];           // block scan workspace (2 KB)
    __shared__ uint stage[EPB];         // staged payloads (16 KB)
    __shared__ ushort sbid[EPB];        // bucket id per staged slot (8 KB)
    int t = threadIdx.x;
    int base = blockIdx.x * EPB;

    int rs[16], rd[16];
#pragma unroll
    for (int j = 0; j < 16; ++j) {
        int e = base + j * 256 + t;
        if (e < N_EDGES) { rs[j] = src[e]; rd[j] = dst[e]; }
        else rd[j] = -1;
    }
    for (int i = t; i < 4 * NB; i += 256) h4[i] = 0;
    __syncthreads();
    int w = t >> 6;
#pragma unroll
    for (int j = 0; j < 16; ++j)
        if (rd[j] >= 0) atomicAdd(&h4[w * NB + (rd[j] >> 8)], 1);
    __syncthreads();

    // combined counts -> scan[512] (padded with zeros)
    for (int b = t; b < 512; b += 256)
        scan[b] = (b < NB) ? (h4[b] + h4[NB + b] + h4[2 * NB + b] + h4[3 * NB + b]) : 0;
    __syncthreads();
    // inclusive Hillis-Steele scan over 512 entries (2 per thread)
#pragma unroll
    for (int o = 1; o < 512; o <<= 1) {
        int a0 = (t >= o) ? scan[t - o] : 0;
        int a1 = (t + 256 >= o) ? scan[t + 256 - o] : 0;
        __syncthreads();
        scan[t] += a0;
        scan[t + 256] += a1;
        __syncthreads();
    }

    // reserve global ranges; set local cursors and flush bases
    for (int b = t; b < NB; b += 256) {
        int cnt = h4[b] + h4[NB + b] + h4[2 * NB + b] + h4[3 * NB + b];
        int loff = scan[b] - cnt;               // exclusive prefix within block
        int start = cnt ? atomicAdd(&bcnt[b * 16], cnt) : 0;
        gbase[b] = b * CAP + start - loff;
        cur[b] = loff;
    }
    __syncthreads();

    // LDS multisplit: stage payloads bucket-contiguously
#pragma unroll
    for (int j = 0; j < 16; ++j) {
        if (rd[j] >= 0) {
            int b = rd[j] >> 8;
            int r = atomicAdd(&cur[b], 1);
            stage[r] = ((uint)(rd[j] & 255) << 24) | (uint)rs[j];   // src < 2^17
            sbid[r] = (ushort)b;
        }
    }
    __syncthreads();

    // coalesced flush: lanes i..i+63 mostly share buckets -> contiguous stores
    int total = scan[NB - 1];
    for (int i = t; i < total; i += 256)
        pairs[(size_t)gbase[sbid[i]] + i] = stage[i];
}

// ---------------------------------------------------------------------------
// Per-bucket CSR build (256-node buckets, 512 threads) — R6-proven:
// pass 1: 8-way wave-replicated LDS histogram, 4-wide batched loads;
// scan -> rstart/rend/dis; pass 2: 4-wide batched cursor fill of csr_src.
__global__ __launch_bounds__(512) void bucket_csr_kernel(const uint* __restrict__ pairs,
                                                         const int* __restrict__ bcnt,
                                                         int* __restrict__ csr_src,
                                                         int* __restrict__ rstart,
                                                         int* __restrict__ rend,
                                                         float* __restrict__ dis) {
    __shared__ int h8[8 * 256];         // replicated histograms (8 KB)
    __shared__ int h[256];              // combined / scan / cursor
    int b = blockIdx.x;
    int t = threadIdx.x;
    int w = t >> 6;                     // wave 0..7
    int e0 = b * CAP;
    int e1 = e0 + bcnt[b * 16];

    for (int i = t; i < 8 * 256; i += 512) h8[i] = 0;
    __syncthreads();

    int* hw = &h8[w * 256];
    int e = e0 + t;
    for (; e + 1536 < e1; e += 2048) {
        uint p0 = pairs[e], p1 = pairs[e + 512], p2 = pairs[e + 1024], p3 = pairs[e + 1536];
        atomicAdd(&hw[p0 >> 24], 1);
        atomicAdd(&hw[p1 >> 24], 1);
        atomicAdd(&hw[p2 >> 24], 1);
        atomicAdd(&hw[p3 >> 24], 1);
    }
    for (; e < e1; e += 512)
        atomicAdd(&hw[pairs[e] >> 24], 1);
    __syncthreads();

    int v = 0;
    if (t < 256) {
#pragma unroll
        for (int j = 0; j < 8; ++j) v += h8[j * 256 + t];
        h[t] = v;
    }
    __syncthreads();
    // inclusive scan of h[256]
#pragma unroll
    for (int o = 1; o < 256; o <<= 1) {
        int x = (t >= o && t < 256) ? h[t - o] : 0;
        __syncthreads();
        if (t < 256) h[t] += x;
        __syncthreads();
    }
    int excl = (t < 256) ? h[t] - v : 0;
    int n = b * 256 + t;
    if (t < 256 && n < N_NODES) {
        rstart[n] = e0 + excl;
        rend[n] = e0 + excl + v;
        dis[n] = rsqrtf((float)v + 1.0f);
    }
    __syncthreads();
    if (t < 256) h[t] = e0 + excl;      // cursor
    __syncthreads();

    e = e0 + t;
    for (; e + 1536 < e1; e += 2048) {
        uint p0 = pairs[e], p1 = pairs[e + 512], p2 = pairs[e + 1024], p3 = pairs[e + 1536];
        int q0 = atomicAdd(&h[p0 >> 24], 1);
        int q1 = atomicAdd(&h[p1 >> 24], 1);
        int q2 = atomicAdd(&h[p2 >> 24], 1);
        int q3 = atomicAdd(&h[p3 >> 24], 1);
        csr_src[q0] = (int)(p0 & 0xFFFFFFu);
        csr_src[q1] = (int)(p1 & 0xFFFFFFu);
        csr_src[q2] = (int)(p2 & 0xFFFFFFu);
        csr_src[q3] = (int)(p3 & 0xFFFFFFu);
    }
    for (; e < e1; e += 512) {
        uint p = pairs[e];
        int pos = atomicAdd(&h[p >> 24], 1);
        csr_src[pos] = (int)(p & 0xFFFFFFu);
    }
}

// ---------------------------------------------------------------------------
// GEMM1: Y[M,64](bf16) = (X[M,128] @ W[128,64]) * dis[row].  X fp32.
// block: 128 rows x 64 ch; thread: 4 rows x 8 ch. Register-prefetch staging.
__global__ __launch_bounds__(256) void gemm1_kernel(const float* __restrict__ X,
                                                    const float* __restrict__ W,
                                                    const float* __restrict__ dis,
                                                    uint* __restrict__ Y) {
    __shared__ float Wl[IN_CH * 64];
    __shared__ float Xs[128 * 33];
    int t = threadIdx.x;
    for (int idx = t; idx < IN_CH * 64; idx += 256) Wl[idx] = W[idx];

    int r0 = (t >> 3) * 4;
    int c0 = (t & 7) * 8;
    int rowBase = blockIdx.x * 128;

    float acc[4][8];
#pragma unroll
    for (int a = 0; a < 4; ++a)
#pragma unroll
        for (int c = 0; c < 8; ++c) acc[a][c] = 0.f;

    int srow = t >> 1;
    int shh = (t & 1) * 16;
    bool sok = (rowBase + srow) < N_NODES;
    const float* xbase = X + (size_t)(rowBase + srow) * IN_CH + shh;

    float4 nx[4];
#pragma unroll
    for (int f = 0; f < 4; ++f)
        nx[f] = sok ? *reinterpret_cast<const float4*>(xbase + f * 4)
                    : make_float4(0.f, 0.f, 0.f, 0.f);

    for (int kc = 0; kc < IN_CH; kc += 32) {
        if (kc) __syncthreads();
#pragma unroll
        for (int f = 0; f < 4; ++f) {
            int o = srow * 33 + shh + f * 4;
            Xs[o] = nx[f].x; Xs[o + 1] = nx[f].y; Xs[o + 2] = nx[f].z; Xs[o + 3] = nx[f].w;
        }
        __syncthreads();
        if (kc + 32 < IN_CH) {
#pragma unroll
            for (int f = 0; f < 4; ++f)
                nx[f] = sok ? *reinterpret_cast<const float4*>(xbase + kc + 32 + f * 4)
                            : make_float4(0.f, 0.f, 0.f, 0.f);
        }
#pragma unroll
        for (int kk = 0; kk < 32; ++kk) {
            const float4 wa = *reinterpret_cast<const float4*>(&Wl[(kc + kk) * 64 + c0]);
            const float4 wb = *reinterpret_cast<const float4*>(&Wl[(kc + kk) * 64 + c0 + 4]);
            float xr[4];
#pragma unroll
            for (int a = 0; a < 4; ++a) xr[a] = Xs[(r0 + a) * 33 + kk];
#pragma unroll
            for (int a = 0; a < 4; ++a) {
                acc[a][0] += xr[a] * wa.x; acc[a][1] += xr[a] * wa.y;
                acc[a][2] += xr[a] * wa.z; acc[a][3] += xr[a] * wa.w;
                acc[a][4] += xr[a] * wb.x; acc[a][5] += xr[a] * wb.y;
                acc[a][6] += xr[a] * wb.z; acc[a][7] += xr[a] * wb.w;
            }
        }
    }
#pragma unroll
    for (int a = 0; a < 4; ++a) {
        int row = rowBase + r0 + a;
        if (row < N_NODES) {
            float d = dis[row];
            uint4 o;
            o.x = pack2(acc[a][0] * d, acc[a][1] * d);
            o.y = pack2(acc[a][2] * d, acc[a][3] * d);
            o.z = pack2(acc[a][4] * d, acc[a][5] * d);
            o.w = pack2(acc[a][6] * d, acc[a][7] * d);
            *reinterpret_cast<uint4*>(Y + (size_t)row * 32 + (t & 7) * 4) = o;
        }
    }
}

// ---------------------------------------------------------------------------
// Fused gather1 + GEMM2, BARRIER-FREE (fixes R8's block-convoy):
// one __syncthreads at kernel start (W2 -> LDS), then each wave is fully
// independent: R0-proven gather loop -> xor-butterfly (all 8 lanes of a
// g-class end with the identical reduced 8 channels) -> relu+bias in-register
// -> in-wave broadcast via __shfl (channel c lives on lane c>>3) -> 64-fma
// matvec against LDS W2 -> one bf16 ushort per lane (64 x 2B = one coalesced
// 128B store). No LDS row, no inter-wave coupling, gemm2 dispatch deleted.
__global__ __launch_bounds__(256) void gather_gemm2_kernel(const int* __restrict__ rstart,
                                                           const int* __restrict__ rend,
                                                           const int* __restrict__ csr_src,
                                                           const float* __restrict__ dis,
                                                           const float* __restrict__ bias,
                                                           const float* __restrict__ W2,
                                                           const uint* __restrict__ A,
                                                           uint* __restrict__ Y) {
    __shared__ float Wl[HID * 64];      // 16 KB
    int t = threadIdx.x;
    for (int idx = t; idx < HID * 64; idx += 256) Wl[idx] = W2[idx];
    __syncthreads();                    // only barrier: before any divergence

    int i = blockIdx.x * 4 + (t >> 6);
    if (i >= N_NODES) return;
    int lane = t & 63;
    int q = lane >> 3;               // which of 8 concurrent edges
    int cu = (lane & 7) * 4;         // uint4 offset in 32-uint row (8 channels)

    float4 bi0 = *reinterpret_cast<const float4*>(&bias[(lane & 7) * 8]);
    float4 bi1 = *reinterpret_cast<const float4*>(&bias[(lane & 7) * 8 + 4]);
    float d = dis[i];

    int e = rstart[i];
    int end = rend[i];

    f32x2 a[4], b[4];
#pragma unroll
    for (int j = 0; j < 4; ++j) { a[j] = (f32x2)0.f; b[j] = (f32x2)0.f; }

    if (q == 0) {                    // self term (already *dis[i])
        uint4 u = *reinterpret_cast<const uint4*>(&A[(size_t)i * 32 + cu]);
        a[0] += up2(u.x); a[1] += up2(u.y); a[2] += up2(u.z); a[3] += up2(u.w);
    }
    for (; e + 16 <= end; e += 16) {
        int s0 = csr_src[e + q];
        int s1 = csr_src[e + 8 + q];
        uint4 u0 = *reinterpret_cast<const uint4*>(&A[(size_t)s0 * 32 + cu]);
        uint4 u1 = *reinterpret_cast<const uint4*>(&A[(size_t)s1 * 32 + cu]);
        a[0] += up2(u0.x); a[1] += up2(u0.y); a[2] += up2(u0.z); a[3] += up2(u0.w);
        b[0] += up2(u1.x); b[1] += up2(u1.y); b[2] += up2(u1.z); b[3] += up2(u1.w);
    }
    for (; e + 8 <= end; e += 8) {
        int s = csr_src[e + q];
        uint4 u = *reinterpret_cast<const uint4*>(&A[(size_t)s * 32 + cu]);
        a[0] += up2(u.x); a[1] += up2(u.y); a[2] += up2(u.z); a[3] += up2(u.w);
    }
    if (e + q < end) {
        int s = csr_src[e + q];
        uint4 u = *reinterpret_cast<const uint4*>(&A[(size_t)s * 32 + cu]);
        b[0] += up2(u.x); b[1] += up2(u.y); b[2] += up2(u.z); b[3] += up2(u.w);
    }
    float r[8];
#pragma unroll
    for (int j = 0; j < 4; ++j) {
        f32x2 s = a[j] + b[j];
        r[2 * j] = s.x; r[2 * j + 1] = s.y;
    }
#pragma unroll
    for (int j = 0; j < 8; ++j) {
        r[j] += __shfl_xor(r[j], 8);
        r[j] += __shfl_xor(r[j], 16);
        r[j] += __shfl_xor(r[j], 32);
    }
    // every lane now has its g-class's 8 reduced channels: apply bias+relu
    float v[8];
    v[0] = fmaxf(bi0.x + d * r[0], 0.f);
    v[1] = fmaxf(bi0.y + d * r[1], 0.f);
    v[2] = fmaxf(bi0.z + d * r[2], 0.f);
    v[3] = fmaxf(bi0.w + d * r[3], 0.f);
    v[4] = fmaxf(bi1.x + d * r[4], 0.f);
    v[5] = fmaxf(bi1.y + d * r[5], 0.f);
    v[6] = fmaxf(bi1.z + d * r[6], 0.f);
    v[7] = fmaxf(bi1.w + d * r[7], 0.f);

    // matvec: out[lane] = sum_c B1row[c] * W2[c][lane];  B1row[c] broadcast
    // from lane c>>3 (any q works; all lanes of a g-class are identical).
    float acc = 0.f;
#pragma unroll
    for (int g = 0; g < 8; ++g)
#pragma unroll
        for (int j = 0; j < 8; ++j) {
            float bc = __shfl(v[j], g);
            acc += bc * Wl[(g * 8 + j) * 64 + lane];
        }
    ((ushort*)Y)[(size_t)i * 64 + lane] = (ushort)f2bf1(acc * d);
}

// ---------------------------------------------------------------------------
// R0-proven gather (layer 2): wave per node, 8 edges concurrent, 16-edge
// unroll, f32x2 packed accumulation.
// B[i] = bf16(bias + dis[i] * (A[i] + sum A[src]))
__global__ __launch_bounds__(256) void gather_kernel(const int* __restrict__ rstart,
                                                     const int* __restrict__ rend,
                                                     const int* __restrict__ csr_src,
                                                     const float* __restrict__ dis,
                                                     const float* __restrict__ bias,
                                                     const uint* __restrict__ A,
                                                     uint* __restrict__ B) {
    int i = blockIdx.x * 4 + (threadIdx.x >> 6);
    if (i >= N_NODES) return;
    int lane = threadIdx.x & 63;
    int q = lane >> 3;               // which of 8 concurrent edges
    int cu = (lane & 7) * 4;         // uint4 offset in 32-uint row (8 channels)

    float4 bi0 = *reinterpret_cast<const float4*>(&bias[(lane & 7) * 8]);
    float4 bi1 = *reinterpret_cast<const float4*>(&bias[(lane & 7) * 8 + 4]);

    int e = rstart[i];
    int end = rend[i];

    f32x2 a[4], b[4];
#pragma unroll
    for (int j = 0; j < 4; ++j) { a[j] = (f32x2)0.f; b[j] = (f32x2)0.f; }

    if (q == 0) {                    // self term (already *dis[i])
        uint4 u = *reinterpret_cast<const uint4*>(&A[(size_t)i * 32 + cu]);
        a[0] += up2(u.x); a[1] += up2(u.y); a[2] += up2(u.z); a[3] += up2(u.w);
    }
    for (; e + 16 <= end; e += 16) {
        int s0 = csr_src[e + q];
        int s1 = csr_src[e + 8 + q];
        uint4 u0 = *reinterpret_cast<const uint4*>(&A[(size_t)s0 * 32 + cu]);
        uint4 u1 = *reinterpret_cast<const uint4*>(&A[(size_t)s1 * 32 + cu]);
        a[0] += up2(u0.x); a[1] += up2(u0.y); a[2] += up2(u0.z); a[3] += up2(u0.w);
        b[0] += up2(u1.x); b[1] += up2(u1.y); b[2] += up2(u1.z); b[3] += up2(u1.w);
    }
    for (; e + 8 <= end; e += 8) {
        int s = csr_src[e + q];
        uint4 u = *reinterpret_cast<const uint4*>(&A[(size_t)s * 32 + cu]);
        a[0] += up2(u.x); a[1] += up2(u.y); a[2] += up2(u.z); a[3] += up2(u.w);
    }
    if (e + q < end) {
        int s = csr_src[e + q];
        uint4 u = *reinterpret_cast<const uint4*>(&A[(size_t)s * 32 + cu]);
        b[0] += up2(u.x); b[1] += up2(u.y); b[2] += up2(u.z); b[3] += up2(u.w);
    }
    float r[8];
#pragma unroll
    for (int j = 0; j < 4; ++j) {
        f32x2 s = a[j] + b[j];
        r[2 * j] = s.x; r[2 * j + 1] = s.y;
    }
#pragma unroll
    for (int j = 0; j < 8; ++j) {
        r[j] += __shfl_xor(r[j], 8);
        r[j] += __shfl_xor(r[j], 16);
        r[j] += __shfl_xor(r[j], 32);
    }
    if (q == 0) {
        float d = dis[i];
        uint4 o;
        o.x = pack2(bi0.x + d * r[0], bi0.y + d * r[1]);
        o.y = pack2(bi0.z + d * r[2], bi0.w + d * r[3]);
        o.z = pack2(bi1.x + d * r[4], bi1.y + d * r[5]);
        o.w = pack2(bi1.z + d * r[6], bi1.w + d * r[7]);
        *reinterpret_cast<uint4*>(B + (size_t)i * 32 + (lane & 7) * 4) = o;
    }
}

// ---------------------------------------------------------------------------
// pool over bf16 B: batch is sorted -> run-length accumulate per half-wave
// (16 nodes each; 32 lanes x 2 ch cover the 64-ch row), relu fused.
__global__ __launch_bounds__(256) void pool_kernel(const uint* __restrict__ B,
                                                   const int* __restrict__ batch,
                                                   float* __restrict__ sums,
                                                   float* __restrict__ cnt) {
    int w = blockIdx.x * 4 + (threadIdx.x >> 6);
    int half = (threadIdx.x >> 5) & 1;
    int l = threadIdx.x & 31;           // uint index (channels 2l, 2l+1)
    int n0 = w * 32 + half * 16;
    if (n0 >= N_NODES) return;
    int n1 = min(n0 + 16, N_NODES);
    int curg = batch[n0];
    float a0 = 0.f, a1 = 0.f;
    int run = 0;
    for (int n = n0; n < n1; ++n) {
        int g = batch[n];
        if (g != curg) {
            atomicAdd(&sums[curg * 64 + 2 * l], a0);
            atomicAdd(&sums[curg * 64 + 2 * l + 1], a1);
            if (l == 0) atomicAdd(&cnt[curg], (float)run);
            curg = g; a0 = 0.f; a1 = 0.f; run = 0;
        }
        float2 f = ub2(B[(size_t)n * 32 + l]);
        a0 += fmaxf(f.x, 0.f);
        a1 += fmaxf(f.y, 0.f);
        run++;
    }
    atomicAdd(&sums[curg * 64 + 2 * l], a0);
    atomicAdd(&sums[curg * 64 + 2 * l + 1], a1);
    if (l == 0) atomicAdd(&cnt[curg], (float)run);
}

__global__ __launch_bounds__(256) void final_kernel(const float* __restrict__ sums,
                                                    const float* __restrict__ cnt,
                                                    float* __restrict__ out) {
    int idx = blockIdx.x * 256 + threadIdx.x;
    if (idx < N_GRAPHS * 64) out[idx] = sums[idx] / fmaxf(cnt[idx >> 6], 1.0f);
}

// ---------------------------------------------------------------------------
extern "C" void kernel_launch(void* const* d_in, const int* in_sizes, int n_in,
                              void* d_out, int out_size, void* d_ws, size_t ws_size,
                              hipStream_t stream) {
    const float* x     = (const float*)d_in[0];
    const int*   edge  = (const int*)d_in[1];   // [2, E]: row0 = src, row1 = dst
    const int*   batch = (const int*)d_in[2];
    const float* W1    = (const float*)d_in[3];
    const float* b1    = (const float*)d_in[4];
    const float* W2    = (const float*)d_in[5];
    const float* b2    = (const float*)d_in[6];
    float* out = (float*)d_out;

    // workspace layout (elements)
    uint*  A        = (uint*)d_ws;                        // 3,200,000 u (bf16, ping)
    uint*  B        = A + (size_t)N_NODES * 32;           // 3,200,000 u (bf16, pong)
    uint*  pairs    = B + (size_t)N_NODES * 32;           // NB*CAP = 4,003,840 u
    int*   csr_src  = (int*)(pairs + (size_t)NB * CAP);   // NB*CAP = 4,003,840 i
    float* dis      = (float*)(csr_src + (size_t)NB * CAP); // 100,000 f
    int*   rstart   = (int*)(dis + N_NODES);              // 100,000 i
    int*   rend     = rstart + N_NODES;                   // 100,000 i
    float* sums     = (float*)(rend + N_NODES);           // 32,768 f
    float* cnt_f    = sums + (size_t)N_GRAPHS * 64;       // 512 f
    int*   bcnt     = (int*)(cnt_f + N_GRAPHS);           // NB*16 = 6,256 i (padded)
    // total ~59 MB

    const int* src = edge;
    const int* dst = edge + N_EDGES;

    // zero sums + cnt + bcnt in one shot (contiguous)
    hipMemsetAsync(sums, 0, (N_GRAPHS * 64 + N_GRAPHS + NB * 16) * sizeof(float), stream);

    // CSR build: coalesced multisplit + per-bucket local fill
    scatter_kernel<<<NBLK, 256, 0, stream>>>(src, dst, bcnt, pairs);
    bucket_csr_kernel<<<NB, 512, 0, stream>>>(pairs, bcnt, csr_src, rstart, rend, dis);

    // layer 1 GEMM: A = bf16((x@W1)*dis)
    gemm1_kernel<<<(N_NODES + 127) / 128, 256, 0, stream>>>(x, W1, dis, A);

    // fused layer-1 gather + layer-2 GEMM (barrier-free):
    // B = bf16((relu(b1 + dis*(A[i] + sum A[src])) @ W2) * dis)
    gather_gemm2_kernel<<<(N_NODES + 3) / 4, 256, 0, stream>>>(
        rstart, rend, csr_src, dis, b1, W2, A, B);

    // layer-2 gather: A = bf16(b2 + dis*(B[i] + sum B[src]))
    gather_kernel<<<(N_NODES + 3) / 4, 256, 0, stream>>>(rstart, rend, csr_src, dis, b2, B, A);

    // pool (relu fused) + finalize
    pool_kernel<<<(N_NODES + 127) / 128, 256, 0, stream>>>(A, batch, sums, cnt_f);
    final_kernel<<<(N_GRAPHS * 64 + 255) / 256, 256, 0, stream>>>(sums, cnt_f, out);
}

// Round 10
// 353.588 us; speedup vs baseline: 1.1585x; 1.1585x over previous
//
#include <hip/hip_runtime.h>

typedef unsigned int uint;
typedef unsigned short ushort;
typedef float f32x2 __attribute__((ext_vector_type(2)));

#define N_NODES 100000
#define N_EDGES 3200000
#define IN_CH 128
#define HID 64
#define N_GRAPHS 512
#define EPB 4096                                   // edges per block (binning)
#define NBLK ((N_EDGES + EPB - 1) / EPB)           // 782
#define NB 391                                     // buckets = dst>>8 (256 nodes each)
#define CAP 10240                                  // bucket capacity (mean 8192, 22 sigma)

// ---------------------------------------------------------------------------
// bf16 helpers: A and B matrices are packed bf16 (uint = 2 channels: 2j, 2j+1)
__device__ __forceinline__ uint f2bf1(float f) {
    union { float f; uint i; } v; v.f = f;
    return (v.i + 0x7fffu + ((v.i >> 16) & 1u)) >> 16;    // RNE
}
__device__ __forceinline__ uint pack2(float lo, float hi) {
    return f2bf1(lo) | (f2bf1(hi) << 16);
}
__device__ __forceinline__ float2 ub2(uint u) {
    union { uint i; float f; } a, b;
    a.i = u << 16; b.i = u & 0xffff0000u;
    return make_float2(a.f, b.f);
}
// unpack to ext-vector float2 (v_pk_add_f32-friendly accumulation)
__device__ __forceinline__ f32x2 up2(uint u) {
    union { uint i; float f; } lo, hi;
    lo.i = u << 16; hi.i = u & 0xffff0000u;
    f32x2 r; r.x = lo.f; r.y = hi.f;
    return r;
}

// ---------------------------------------------------------------------------
// Coalesced multisplit scatter (R5/R6-proven): histogram + global reservation,
// block-local scan -> LDS multisplit into bucket-contiguous runs -> coalesced
// flush (consecutive lanes, same bucket).
__global__ __launch_bounds__(256) void scatter_kernel(const int* __restrict__ src,
                                                      const int* __restrict__ dst,
                                                      int* __restrict__ bcnt,
                                                      uint* __restrict__ pairs) {
    __shared__ int h4[4 * NB];          // replicated histograms (6.3 KB)
    __shared__ int gbase[NB];           // b*CAP + start - loff (1.6 KB)
    __shared__ int cur[NB];             // local cursor, starts at loff (1.6 KB)
    __shared__ int scan[512];           // block scan workspace (2 KB)
    __shared__ uint stage[EPB];         // staged payloads (16 KB)
    __shared__ ushort sbid[EPB];        // bucket id per staged slot (8 KB)
    int t = threadIdx.x;
    int base = blockIdx.x * EPB;

    int rs[16], rd[16];
#pragma unroll
    for (int j = 0; j < 16; ++j) {
        int e = base + j * 256 + t;
        if (e < N_EDGES) { rs[j] = src[e]; rd[j] = dst[e]; }
        else rd[j] = -1;
    }
    for (int i = t; i < 4 * NB; i += 256) h4[i] = 0;
    __syncthreads();
    int w = t >> 6;
#pragma unroll
    for (int j = 0; j < 16; ++j)
        if (rd[j] >= 0) atomicAdd(&h4[w * NB + (rd[j] >> 8)], 1);
    __syncthreads();

    // combined counts -> scan[512] (padded with zeros)
    for (int b = t; b < 512; b += 256)
        scan[b] = (b < NB) ? (h4[b] + h4[NB + b] + h4[2 * NB + b] + h4[3 * NB + b]) : 0;
    __syncthreads();
    // inclusive Hillis-Steele scan over 512 entries (2 per thread)
#pragma unroll
    for (int o = 1; o < 512; o <<= 1) {
        int a0 = (t >= o) ? scan[t - o] : 0;
        int a1 = (t + 256 >= o) ? scan[t + 256 - o] : 0;
        __syncthreads();
        scan[t] += a0;
        scan[t + 256] += a1;
        __syncthreads();
    }

    // reserve global ranges; set local cursors and flush bases
    for (int b = t; b < NB; b += 256) {
        int cnt = h4[b] + h4[NB + b] + h4[2 * NB + b] + h4[3 * NB + b];
        int loff = scan[b] - cnt;               // exclusive prefix within block
        int start = cnt ? atomicAdd(&bcnt[b * 16], cnt) : 0;
        gbase[b] = b * CAP + start - loff;
        cur[b] = loff;
    }
    __syncthreads();

    // LDS multisplit: stage payloads bucket-contiguously
#pragma unroll
    for (int j = 0; j < 16; ++j) {
        if (rd[j] >= 0) {
            int b = rd[j] >> 8;
            int r = atomicAdd(&cur[b], 1);
            stage[r] = ((uint)(rd[j] & 255) << 24) | (uint)rs[j];   // src < 2^17
            sbid[r] = (ushort)b;
        }
    }
    __syncthreads();

    // coalesced flush: lanes i..i+63 mostly share buckets -> contiguous stores
    int total = scan[NB - 1];
    for (int i = t; i < total; i += 256)
        pairs[(size_t)gbase[sbid[i]] + i] = stage[i];
}

// ---------------------------------------------------------------------------
// Per-bucket CSR build (256-node buckets, 512 threads) — R6-proven:
// pass 1: 8-way wave-replicated LDS histogram, 4-wide batched loads;
// scan -> rstart/rend/dis; pass 2: 4-wide batched cursor fill of csr_src.
__global__ __launch_bounds__(512) void bucket_csr_kernel(const uint* __restrict__ pairs,
                                                         const int* __restrict__ bcnt,
                                                         int* __restrict__ csr_src,
                                                         int* __restrict__ rstart,
                                                         int* __restrict__ rend,
                                                         float* __restrict__ dis) {
    __shared__ int h8[8 * 256];         // replicated histograms (8 KB)
    __shared__ int h[256];              // combined / scan / cursor
    int b = blockIdx.x;
    int t = threadIdx.x;
    int w = t >> 6;                     // wave 0..7
    int e0 = b * CAP;
    int e1 = e0 + bcnt[b * 16];

    for (int i = t; i < 8 * 256; i += 512) h8[i] = 0;
    __syncthreads();

    int* hw = &h8[w * 256];
    int e = e0 + t;
    for (; e + 1536 < e1; e += 2048) {
        uint p0 = pairs[e], p1 = pairs[e + 512], p2 = pairs[e + 1024], p3 = pairs[e + 1536];
        atomicAdd(&hw[p0 >> 24], 1);
        atomicAdd(&hw[p1 >> 24], 1);
        atomicAdd(&hw[p2 >> 24], 1);
        atomicAdd(&hw[p3 >> 24], 1);
    }
    for (; e < e1; e += 512)
        atomicAdd(&hw[pairs[e] >> 24], 1);
    __syncthreads();

    int v = 0;
    if (t < 256) {
#pragma unroll
        for (int j = 0; j < 8; ++j) v += h8[j * 256 + t];
        h[t] = v;
    }
    __syncthreads();
    // inclusive scan of h[256]
#pragma unroll
    for (int o = 1; o < 256; o <<= 1) {
        int x = (t >= o && t < 256) ? h[t - o] : 0;
        __syncthreads();
        if (t < 256) h[t] += x;
        __syncthreads();
    }
    int excl = (t < 256) ? h[t] - v : 0;
    int n = b * 256 + t;
    if (t < 256 && n < N_NODES) {
        rstart[n] = e0 + excl;
        rend[n] = e0 + excl + v;
        dis[n] = rsqrtf((float)v + 1.0f);
    }
    __syncthreads();
    if (t < 256) h[t] = e0 + excl;      // cursor
    __syncthreads();

    e = e0 + t;
    for (; e + 1536 < e1; e += 2048) {
        uint p0 = pairs[e], p1 = pairs[e + 512], p2 = pairs[e + 1024], p3 = pairs[e + 1536];
        int q0 = atomicAdd(&h[p0 >> 24], 1);
        int q1 = atomicAdd(&h[p1 >> 24], 1);
        int q2 = atomicAdd(&h[p2 >> 24], 1);
        int q3 = atomicAdd(&h[p3 >> 24], 1);
        csr_src[q0] = (int)(p0 & 0xFFFFFFu);
        csr_src[q1] = (int)(p1 & 0xFFFFFFu);
        csr_src[q2] = (int)(p2 & 0xFFFFFFu);
        csr_src[q3] = (int)(p3 & 0xFFFFFFu);
    }
    for (; e < e1; e += 512) {
        uint p = pairs[e];
        int pos = atomicAdd(&h[p >> 24], 1);
        csr_src[pos] = (int)(p & 0xFFFFFFu);
    }
}

// ---------------------------------------------------------------------------
// GEMM1: Y[M,64](bf16) = (X[M,128] @ W[128,64]) * dis[row].  X fp32.
// block: 128 rows x 64 ch; thread: 4 rows x 8 ch. Register-prefetch staging.
__global__ __launch_bounds__(256) void gemm1_kernel(const float* __restrict__ X,
                                                    const float* __restrict__ W,
                                                    const float* __restrict__ dis,
                                                    uint* __restrict__ Y) {
    __shared__ float Wl[IN_CH * 64];
    __shared__ float Xs[128 * 33];
    int t = threadIdx.x;
    for (int idx = t; idx < IN_CH * 64; idx += 256) Wl[idx] = W[idx];

    int r0 = (t >> 3) * 4;
    int c0 = (t & 7) * 8;
    int rowBase = blockIdx.x * 128;

    float acc[4][8];
#pragma unroll
    for (int a = 0; a < 4; ++a)
#pragma unroll
        for (int c = 0; c < 8; ++c) acc[a][c] = 0.f;

    int srow = t >> 1;
    int shh = (t & 1) * 16;
    bool sok = (rowBase + srow) < N_NODES;
    const float* xbase = X + (size_t)(rowBase + srow) * IN_CH + shh;

    float4 nx[4];
#pragma unroll
    for (int f = 0; f < 4; ++f)
        nx[f] = sok ? *reinterpret_cast<const float4*>(xbase + f * 4)
                    : make_float4(0.f, 0.f, 0.f, 0.f);

    for (int kc = 0; kc < IN_CH; kc += 32) {
        if (kc) __syncthreads();
#pragma unroll
        for (int f = 0; f < 4; ++f) {
            int o = srow * 33 + shh + f * 4;
            Xs[o] = nx[f].x; Xs[o + 1] = nx[f].y; Xs[o + 2] = nx[f].z; Xs[o + 3] = nx[f].w;
        }
        __syncthreads();
        if (kc + 32 < IN_CH) {
#pragma unroll
            for (int f = 0; f < 4; ++f)
                nx[f] = sok ? *reinterpret_cast<const float4*>(xbase + kc + 32 + f * 4)
                            : make_float4(0.f, 0.f, 0.f, 0.f);
        }
#pragma unroll
        for (int kk = 0; kk < 32; ++kk) {
            const float4 wa = *reinterpret_cast<const float4*>(&Wl[(kc + kk) * 64 + c0]);
            const float4 wb = *reinterpret_cast<const float4*>(&Wl[(kc + kk) * 64 + c0 + 4]);
            float xr[4];
#pragma unroll
            for (int a = 0; a < 4; ++a) xr[a] = Xs[(r0 + a) * 33 + kk];
#pragma unroll
            for (int a = 0; a < 4; ++a) {
                acc[a][0] += xr[a] * wa.x; acc[a][1] += xr[a] * wa.y;
                acc[a][2] += xr[a] * wa.z; acc[a][3] += xr[a] * wa.w;
                acc[a][4] += xr[a] * wb.x; acc[a][5] += xr[a] * wb.y;
                acc[a][6] += xr[a] * wb.z; acc[a][7] += xr[a] * wb.w;
            }
        }
    }
#pragma unroll
    for (int a = 0; a < 4; ++a) {
        int row = rowBase + r0 + a;
        if (row < N_NODES) {
            float d = dis[row];
            uint4 o;
            o.x = pack2(acc[a][0] * d, acc[a][1] * d);
            o.y = pack2(acc[a][2] * d, acc[a][3] * d);
            o.z = pack2(acc[a][4] * d, acc[a][5] * d);
            o.w = pack2(acc[a][6] * d, acc[a][7] * d);
            *reinterpret_cast<uint4*>(Y + (size_t)row * 32 + (t & 7) * 4) = o;
        }
    }
}

// ---------------------------------------------------------------------------
// GEMM2: Y[M,64](bf16) = (relu(X)[M,64] @ W[64,64]) * dis[row].  X bf16 packed.
__global__ __launch_bounds__(256) void gemm2_kernel(const uint* __restrict__ X,
                                                    const float* __restrict__ W,
                                                    const float* __restrict__ dis,
                                                    uint* __restrict__ Y) {
    __shared__ float Wl[HID * 64];
    __shared__ float Xs[128 * 33];
    int t = threadIdx.x;
    for (int idx = t; idx < HID * 64; idx += 256) Wl[idx] = W[idx];

    int r0 = (t >> 3) * 4;
    int c0 = (t & 7) * 8;
    int rowBase = blockIdx.x * 128;

    float acc[4][8];
#pragma unroll
    for (int a = 0; a < 4; ++a)
#pragma unroll
        for (int c = 0; c < 8; ++c) acc[a][c] = 0.f;

    int srow = t >> 1;
    int shh = (t & 1) * 16;
    bool sok = (rowBase + srow) < N_NODES;
    const uint* xbase = X + (size_t)(rowBase + srow) * 32 + (t & 1) * 8;

    uint4 n0_ = make_uint4(0, 0, 0, 0), n1_ = n0_;
    if (sok) {
        n0_ = *reinterpret_cast<const uint4*>(xbase);
        n1_ = *reinterpret_cast<const uint4*>(xbase + 4);
    }

    for (int kc = 0; kc < HID; kc += 32) {
        if (kc) __syncthreads();
        {
            uint us[8] = {n0_.x, n0_.y, n0_.z, n0_.w, n1_.x, n1_.y, n1_.z, n1_.w};
            int o = srow * 33 + shh;
#pragma unroll
            for (int j = 0; j < 8; ++j) {
                float2 f = ub2(us[j]);
                Xs[o + 2 * j]     = fmaxf(f.x, 0.f);
                Xs[o + 2 * j + 1] = fmaxf(f.y, 0.f);
            }
        }
        __syncthreads();
        if (kc + 32 < HID && sok) {
            n0_ = *reinterpret_cast<const uint4*>(xbase + 16);
            n1_ = *reinterpret_cast<const uint4*>(xbase + 20);
        }
#pragma unroll
        for (int kk = 0; kk < 32; ++kk) {
            const float4 wa = *reinterpret_cast<const float4*>(&Wl[(kc + kk) * 64 + c0]);
            const float4 wb = *reinterpret_cast<const float4*>(&Wl[(kc + kk) * 64 + c0 + 4]);
            float xr[4];
#pragma unroll
            for (int a = 0; a < 4; ++a) xr[a] = Xs[(r0 + a) * 33 + kk];
#pragma unroll
            for (int a = 0; a < 4; ++a) {
                acc[a][0] += xr[a] * wa.x; acc[a][1] += xr[a] * wa.y;
                acc[a][2] += xr[a] * wa.z; acc[a][3] += xr[a] * wa.w;
                acc[a][4] += xr[a] * wb.x; acc[a][5] += xr[a] * wb.y;
                acc[a][6] += xr[a] * wb.z; acc[a][7] += xr[a] * wb.w;
            }
        }
    }
#pragma unroll
    for (int a = 0; a < 4; ++a) {
        int row = rowBase + r0 + a;
        if (row < N_NODES) {
            float d = dis[row];
            uint4 o;
            o.x = pack2(acc[a][0] * d, acc[a][1] * d);
            o.y = pack2(acc[a][2] * d, acc[a][3] * d);
            o.z = pack2(acc[a][4] * d, acc[a][5] * d);
            o.w = pack2(acc[a][6] * d, acc[a][7] * d);
            *reinterpret_cast<uint4*>(Y + (size_t)row * 32 + (t & 7) * 4) = o;
        }
    }
}

// ---------------------------------------------------------------------------
// R0-proven gather: wave per node, 8 edges concurrent (8 lanes/edge, bf16x8 =
// 16B per lane), 16-edge unroll, f32x2 packed accumulation (v_pk_add_f32):
// B[i] = bf16(bias + dis[i] * (A[i] + sum A[src])),  A = (X@W)*dis  (bf16)
__global__ __launch_bounds__(256) void gather_kernel(const int* __restrict__ rstart,
                                                     const int* __restrict__ rend,
                                                     const int* __restrict__ csr_src,
                                                     const float* __restrict__ dis,
                                                     const float* __restrict__ bias,
                                                     const uint* __restrict__ A,
                                                     uint* __restrict__ B) {
    int i = blockIdx.x * 4 + (threadIdx.x >> 6);
    if (i >= N_NODES) return;
    int lane = threadIdx.x & 63;
    int q = lane >> 3;               // which of 8 concurrent edges
    int cu = (lane & 7) * 4;         // uint4 offset in 32-uint row (8 channels)

    float4 bi0 = *reinterpret_cast<const float4*>(&bias[(lane & 7) * 8]);
    float4 bi1 = *reinterpret_cast<const float4*>(&bias[(lane & 7) * 8 + 4]);

    int e = rstart[i];
    int end = rend[i];

    f32x2 a[4], b[4];
#pragma unroll
    for (int j = 0; j < 4; ++j) { a[j] = (f32x2)0.f; b[j] = (f32x2)0.f; }

    if (q == 0) {                    // self term (already *dis[i])
        uint4 u = *reinterpret_cast<const uint4*>(&A[(size_t)i * 32 + cu]);
        a[0] += up2(u.x); a[1] += up2(u.y); a[2] += up2(u.z); a[3] += up2(u.w);
    }
    for (; e + 16 <= end; e += 16) {
        int s0 = csr_src[e + q];
        int s1 = csr_src[e + 8 + q];
        uint4 u0 = *reinterpret_cast<const uint4*>(&A[(size_t)s0 * 32 + cu]);
        uint4 u1 = *reinterpret_cast<const uint4*>(&A[(size_t)s1 * 32 + cu]);
        a[0] += up2(u0.x); a[1] += up2(u0.y); a[2] += up2(u0.z); a[3] += up2(u0.w);
        b[0] += up2(u1.x); b[1] += up2(u1.y); b[2] += up2(u1.z); b[3] += up2(u1.w);
    }
    for (; e + 8 <= end; e += 8) {
        int s = csr_src[e + q];
        uint4 u = *reinterpret_cast<const uint4*>(&A[(size_t)s * 32 + cu]);
        a[0] += up2(u.x); a[1] += up2(u.y); a[2] += up2(u.z); a[3] += up2(u.w);
    }
    if (e + q < end) {
        int s = csr_src[e + q];
        uint4 u = *reinterpret_cast<const uint4*>(&A[(size_t)s * 32 + cu]);
        b[0] += up2(u.x); b[1] += up2(u.y); b[2] += up2(u.z); b[3] += up2(u.w);
    }
    float r[8];
#pragma unroll
    for (int j = 0; j < 4; ++j) {
        f32x2 s = a[j] + b[j];
        r[2 * j] = s.x; r[2 * j + 1] = s.y;
    }
#pragma unroll
    for (int j = 0; j < 8; ++j) {
        r[j] += __shfl_xor(r[j], 8);
        r[j] += __shfl_xor(r[j], 16);
        r[j] += __shfl_xor(r[j], 32);
    }
    if (q == 0) {
        float d = dis[i];
        uint4 o;
        o.x = pack2(bi0.x + d * r[0], bi0.y + d * r[1]);
        o.y = pack2(bi0.z + d * r[2], bi0.w + d * r[3]);
        o.z = pack2(bi1.x + d * r[4], bi1.y + d * r[5]);
        o.w = pack2(bi1.z + d * r[6], bi1.w + d * r[7]);
        *reinterpret_cast<uint4*>(B + (size_t)i * 32 + (lane & 7) * 4) = o;
    }
}

// ---------------------------------------------------------------------------
// Atomic-free pool + finalize: ONE BLOCK PER GRAPH (batch is sorted).
// Two binary searches find the graph's node range [lo, hi); 8 half-waves
// stride the rows (coalesced 128B reads), accumulate relu in registers;
// 2KB LDS tree-reduce; direct store of out[g] = sum / max(cnt,1).
// Zero atomics, zero contention; replaces pool_kernel + final_kernel +
// the sums/cnt memset.
__global__ __launch_bounds__(256) void pool_final_kernel(const uint* __restrict__ B,
                                                         const int* __restrict__ batch,
                                                         float* __restrict__ out) {
    __shared__ float part[8][64];       // per-half-wave partials (2 KB)
    int g = blockIdx.x;
    int t = threadIdx.x;
    int hw = t >> 5;                    // half-wave 0..7
    int l = t & 31;                     // uint column (channels 2l, 2l+1)

    // lower_bound(batch, g) and lower_bound(batch, g+1) — uniform branches
    int a = 0, b = N_NODES;
    while (a < b) { int m = (a + b) >> 1; if (batch[m] < g) a = m + 1; else b = m; }
    int lo = a;
    b = N_NODES;
    while (a < b) { int m = (a + b) >> 1; if (batch[m] < g + 1) a = m + 1; else b = m; }
    int hi = a;

    float a0 = 0.f, a1 = 0.f;
    for (int n = lo + hw; n < hi; n += 8) {
        float2 f = ub2(B[(size_t)n * 32 + l]);
        a0 += fmaxf(f.x, 0.f);
        a1 += fmaxf(f.y, 0.f);
    }
    part[hw][2 * l] = a0;
    part[hw][2 * l + 1] = a1;
    __syncthreads();

    if (t < 64) {
        float s = 0.f;
#pragma unroll
        for (int j = 0; j < 8; ++j) s += part[j][t];
        out[g * 64 + t] = s / fmaxf((float)(hi - lo), 1.0f);
    }
}

// ---------------------------------------------------------------------------
extern "C" void kernel_launch(void* const* d_in, const int* in_sizes, int n_in,
                              void* d_out, int out_size, void* d_ws, size_t ws_size,
                              hipStream_t stream) {
    const float* x     = (const float*)d_in[0];
    const int*   edge  = (const int*)d_in[1];   // [2, E]: row0 = src, row1 = dst
    const int*   batch = (const int*)d_in[2];
    const float* W1    = (const float*)d_in[3];
    const float* b1    = (const float*)d_in[4];
    const float* W2    = (const float*)d_in[5];
    const float* b2    = (const float*)d_in[6];
    float* out = (float*)d_out;

    // workspace layout (elements)
    uint*  A        = (uint*)d_ws;                        // 3,200,000 u (bf16, ping)
    uint*  B        = A + (size_t)N_NODES * 32;           // 3,200,000 u (bf16, pong)
    uint*  pairs    = B + (size_t)N_NODES * 32;           // NB*CAP = 4,003,840 u
    int*   csr_src  = (int*)(pairs + (size_t)NB * CAP);   // NB*CAP = 4,003,840 i
    float* dis      = (float*)(csr_src + (size_t)NB * CAP); // 100,000 f
    int*   rstart   = (int*)(dis + N_NODES);              // 100,000 i
    int*   rend     = rstart + N_NODES;                   // 100,000 i
    int*   bcnt     = rend + N_NODES;                     // NB*16 = 6,256 i (padded)
    // total ~59 MB

    const int* src = edge;
    const int* dst = edge + N_EDGES;

    // zero bucket counters only (sums/cnt no longer exist)
    hipMemsetAsync(bcnt, 0, NB * 16 * sizeof(int), stream);

    // CSR build: coalesced multisplit + per-bucket local fill
    scatter_kernel<<<NBLK, 256, 0, stream>>>(src, dst, bcnt, pairs);
    bucket_csr_kernel<<<NB, 512, 0, stream>>>(pairs, bcnt, csr_src, rstart, rend, dis);

    // layer 1: A = bf16((x@W1)*dis) ; B = bf16(b1 + dis*(A[i] + sum A[src]))
    gemm1_kernel<<<(N_NODES + 127) / 128, 256, 0, stream>>>(x, W1, dis, A);
    gather_kernel<<<(N_NODES + 3) / 4, 256, 0, stream>>>(rstart, rend, csr_src, dis, b1, A, B);

    // layer 2 (relu fused into GEMM2 staging)
    gemm2_kernel<<<(N_NODES + 127) / 128, 256, 0, stream>>>(B, W2, dis, A);
    gather_kernel<<<(N_NODES + 3) / 4, 256, 0, stream>>>(rstart, rend, csr_src, dis, b2, A, B);

    // atomic-free pool + finalize (one block per graph, direct store)
    pool_final_kernel<<<N_GRAPHS, 256, 0, stream>>>(B, batch, out);
}

// Round 13
// 347.280 us; speedup vs baseline: 1.1795x; 1.0182x over previous
//
#include <hip/hip_runtime.h>

typedef unsigned int uint;
typedef unsigned short ushort;
typedef float f32x2 __attribute__((ext_vector_type(2)));

#define N_NODES 100000
#define N_EDGES 3200000
#define IN_CH 128
#define HID 64
#define N_GRAPHS 512
#define EPB 4096                                   // edges per block (binning)
#define NBLK ((N_EDGES + EPB - 1) / EPB)           // 782
#define NB 391                                     // buckets = dst>>8 (256 nodes each)
#define CAP 10240                                  // bucket capacity (mean 8192, 22 sigma)

// ---------------------------------------------------------------------------
// bf16 helpers: A and B matrices are packed bf16 (uint = 2 channels: 2j, 2j+1)
__device__ __forceinline__ uint f2bf1(float f) {
    union { float f; uint i; } v; v.f = f;
    return (v.i + 0x7fffu + ((v.i >> 16) & 1u)) >> 16;    // RNE
}
__device__ __forceinline__ uint pack2(float lo, float hi) {
    return f2bf1(lo) | (f2bf1(hi) << 16);
}
__device__ __forceinline__ float2 ub2(uint u) {
    union { uint i; float f; } a, b;
    a.i = u << 16; b.i = u & 0xffff0000u;
    return make_float2(a.f, b.f);
}
// unpack to ext-vector float2 (v_pk_add_f32-friendly accumulation)
__device__ __forceinline__ f32x2 up2(uint u) {
    union { uint i; float f; } lo, hi;
    lo.i = u << 16; hi.i = u & 0xffff0000u;
    f32x2 r; r.x = lo.f; r.y = hi.f;
    return r;
}

// ---------------------------------------------------------------------------
// Coalesced multisplit scatter (R5/R6-proven): histogram + global reservation,
// block-local scan -> LDS multisplit into bucket-contiguous runs -> coalesced
// flush (consecutive lanes, same bucket).
__global__ __launch_bounds__(256) void scatter_kernel(const int* __restrict__ src,
                                                      const int* __restrict__ dst,
                                                      int* __restrict__ bcnt,
                                                      uint* __restrict__ pairs) {
    __shared__ int h4[4 * NB];          // replicated histograms (6.3 KB)
    __shared__ int gbase[NB];           // b*CAP + start - loff (1.6 KB)
    __shared__ int cur[NB];             // local cursor, starts at loff (1.6 KB)
    __shared__ int scan[512];           // block scan workspace (2 KB)
    __shared__ uint stage[EPB];         // staged payloads (16 KB)
    __shared__ ushort sbid[EPB];        // bucket id per staged slot (8 KB)
    int t = threadIdx.x;
    int base = blockIdx.x * EPB;

    int rs[16], rd[16];
#pragma unroll
    for (int j = 0; j < 16; ++j) {
        int e = base + j * 256 + t;
        if (e < N_EDGES) { rs[j] = src[e]; rd[j] = dst[e]; }
        else rd[j] = -1;
    }
    for (int i = t; i < 4 * NB; i += 256) h4[i] = 0;
    __syncthreads();
    int w = t >> 6;
#pragma unroll
    for (int j = 0; j < 16; ++j)
        if (rd[j] >= 0) atomicAdd(&h4[w * NB + (rd[j] >> 8)], 1);
    __syncthreads();

    // combined counts -> scan[512] (padded with zeros)
    for (int b = t; b < 512; b += 256)
        scan[b] = (b < NB) ? (h4[b] + h4[NB + b] + h4[2 * NB + b] + h4[3 * NB + b]) : 0;
    __syncthreads();
    // inclusive Hillis-Steele scan over 512 entries (2 per thread)
#pragma unroll
    for (int o = 1; o < 512; o <<= 1) {
        int a0 = (t >= o) ? scan[t - o] : 0;
        int a1 = (t + 256 >= o) ? scan[t + 256 - o] : 0;
        __syncthreads();
        scan[t] += a0;
        scan[t + 256] += a1;
        __syncthreads();
    }

    // reserve global ranges; set local cursors and flush bases
    for (int b = t; b < NB; b += 256) {
        int cnt = h4[b] + h4[NB + b] + h4[2 * NB + b] + h4[3 * NB + b];
        int loff = scan[b] - cnt;               // exclusive prefix within block
        int start = cnt ? atomicAdd(&bcnt[b * 16], cnt) : 0;
        gbase[b] = b * CAP + start - loff;
        cur[b] = loff;
    }
    __syncthreads();

    // LDS multisplit: stage payloads bucket-contiguously
#pragma unroll
    for (int j = 0; j < 16; ++j) {
        if (rd[j] >= 0) {
            int b = rd[j] >> 8;
            int r = atomicAdd(&cur[b], 1);
            stage[r] = ((uint)(rd[j] & 255) << 24) | (uint)rs[j];   // src < 2^17
            sbid[r] = (ushort)b;
        }
    }
    __syncthreads();

    // coalesced flush: lanes i..i+63 mostly share buckets -> contiguous stores
    int total = scan[NB - 1];
    for (int i = t; i < total; i += 256)
        pairs[(size_t)gbase[sbid[i]] + i] = stage[i];
}

// ---------------------------------------------------------------------------
// Per-bucket CSR build (256-node buckets, 512 threads) — R6-proven:
// pass 1: 8-way wave-replicated LDS histogram, 4-wide batched loads;
// scan -> rstart/rend/dis; pass 2: 4-wide batched cursor fill of csr_src.
__global__ __launch_bounds__(512) void bucket_csr_kernel(const uint* __restrict__ pairs,
                                                         const int* __restrict__ bcnt,
                                                         int* __restrict__ csr_src,
                                                         int* __restrict__ rstart,
                                                         int* __restrict__ rend,
                                                         float* __restrict__ dis) {
    __shared__ int h8[8 * 256];         // replicated histograms (8 KB)
    __shared__ int h[256];              // combined / scan / cursor
    int b = blockIdx.x;
    int t = threadIdx.x;
    int w = t >> 6;                     // wave 0..7
    int e0 = b * CAP;
    int e1 = e0 + bcnt[b * 16];

    for (int i = t; i < 8 * 256; i += 512) h8[i] = 0;
    __syncthreads();

    int* hw = &h8[w * 256];
    int e = e0 + t;
    for (; e + 1536 < e1; e += 2048) {
        uint p0 = pairs[e], p1 = pairs[e + 512], p2 = pairs[e + 1024], p3 = pairs[e + 1536];
        atomicAdd(&hw[p0 >> 24], 1);
        atomicAdd(&hw[p1 >> 24], 1);
        atomicAdd(&hw[p2 >> 24], 1);
        atomicAdd(&hw[p3 >> 24], 1);
    }
    for (; e < e1; e += 512)
        atomicAdd(&hw[pairs[e] >> 24], 1);
    __syncthreads();

    int v = 0;
    if (t < 256) {
#pragma unroll
        for (int j = 0; j < 8; ++j) v += h8[j * 256 + t];
        h[t] = v;
    }
    __syncthreads();
    // inclusive scan of h[256]
#pragma unroll
    for (int o = 1; o < 256; o <<= 1) {
        int x = (t >= o && t < 256) ? h[t - o] : 0;
        __syncthreads();
        if (t < 256) h[t] += x;
        __syncthreads();
    }
    int excl = (t < 256) ? h[t] - v : 0;
    int n = b * 256 + t;
    if (t < 256 && n < N_NODES) {
        rstart[n] = e0 + excl;
        rend[n] = e0 + excl + v;
        dis[n] = rsqrtf((float)v + 1.0f);
    }
    __syncthreads();
    if (t < 256) h[t] = e0 + excl;      // cursor
    __syncthreads();

    e = e0 + t;
    for (; e + 1536 < e1; e += 2048) {
        uint p0 = pairs[e], p1 = pairs[e + 512], p2 = pairs[e + 1024], p3 = pairs[e + 1536];
        int q0 = atomicAdd(&h[p0 >> 24], 1);
        int q1 = atomicAdd(&h[p1 >> 24], 1);
        int q2 = atomicAdd(&h[p2 >> 24], 1);
        int q3 = atomicAdd(&h[p3 >> 24], 1);
        csr_src[q0] = (int)(p0 & 0xFFFFFFu);
        csr_src[q1] = (int)(p1 & 0xFFFFFFu);
        csr_src[q2] = (int)(p2 & 0xFFFFFFu);
        csr_src[q3] = (int)(p3 & 0xFFFFFFu);
    }
    for (; e < e1; e += 512) {
        uint p = pairs[e];
        int pos = atomicAdd(&h[p >> 24], 1);
        csr_src[pos] = (int)(p & 0xFFFFFFu);
    }
}

// ---------------------------------------------------------------------------
// GEMM1: Y[M,64](bf16) = (X[M,128] @ W[128,64]) * dis[row].  X fp32.
// block: 128 rows x 64 ch; thread: 4 rows x 8 ch. Register-prefetch staging.
__global__ __launch_bounds__(256) void gemm1_kernel(const float* __restrict__ X,
                                                    const float* __restrict__ W,
                                                    const float* __restrict__ dis,
                                                    uint* __restrict__ Y) {
    __shared__ float Wl[IN_CH * 64];
    __shared__ float Xs[128 * 33];
    int t = threadIdx.x;
    for (int idx = t; idx < IN_CH * 64; idx += 256) Wl[idx] = W[idx];

    int r0 = (t >> 3) * 4;
    int c0 = (t & 7) * 8;
    int rowBase = blockIdx.x * 128;

    float acc[4][8];
#pragma unroll
    for (int a = 0; a < 4; ++a)
#pragma unroll
        for (int c = 0; c < 8; ++c) acc[a][c] = 0.f;

    int srow = t >> 1;
    int shh = (t & 1) * 16;
    bool sok = (rowBase + srow) < N_NODES;
    const float* xbase = X + (size_t)(rowBase + srow) * IN_CH + shh;

    float4 nx[4];
#pragma unroll
    for (int f = 0; f < 4; ++f)
        nx[f] = sok ? *reinterpret_cast<const float4*>(xbase + f * 4)
                    : make_float4(0.f, 0.f, 0.f, 0.f);

    for (int kc = 0; kc < IN_CH; kc += 32) {
        if (kc) __syncthreads();
#pragma unroll
        for (int f = 0; f < 4; ++f) {
            int o = srow * 33 + shh + f * 4;
            Xs[o] = nx[f].x; Xs[o + 1] = nx[f].y; Xs[o + 2] = nx[f].z; Xs[o + 3] = nx[f].w;
        }
        __syncthreads();
        if (kc + 32 < IN_CH) {
#pragma unroll
            for (int f = 0; f < 4; ++f)
                nx[f] = sok ? *reinterpret_cast<const float4*>(xbase + kc + 32 + f * 4)
                            : make_float4(0.f, 0.f, 0.f, 0.f);
        }
#pragma unroll
        for (int kk = 0; kk < 32; ++kk) {
            const float4 wa = *reinterpret_cast<const float4*>(&Wl[(kc + kk) * 64 + c0]);
            const float4 wb = *reinterpret_cast<const float4*>(&Wl[(kc + kk) * 64 + c0 + 4]);
            float xr[4];
#pragma unroll
            for (int a = 0; a < 4; ++a) xr[a] = Xs[(r0 + a) * 33 + kk];
#pragma unroll
            for (int a = 0; a < 4; ++a) {
                acc[a][0] += xr[a] * wa.x; acc[a][1] += xr[a] * wa.y;
                acc[a][2] += xr[a] * wa.z; acc[a][3] += xr[a] * wa.w;
                acc[a][4] += xr[a] * wb.x; acc[a][5] += xr[a] * wb.y;
                acc[a][6] += xr[a] * wb.z; acc[a][7] += xr[a] * wb.w;
            }
        }
    }
#pragma unroll
    for (int a = 0; a < 4; ++a) {
        int row = rowBase + r0 + a;
        if (row < N_NODES) {
            float d = dis[row];
            uint4 o;
            o.x = pack2(acc[a][0] * d, acc[a][1] * d);
            o.y = pack2(acc[a][2] * d, acc[a][3] * d);
            o.z = pack2(acc[a][4] * d, acc[a][5] * d);
            o.w = pack2(acc[a][6] * d, acc[a][7] * d);
            *reinterpret_cast<uint4*>(Y + (size_t)row * 32 + (t & 7) * 4) = o;
        }
    }
}

// ---------------------------------------------------------------------------
// GEMM2 (single-staged, K=64): Y[M,64](bf16) = (relu(X)[M,64] @ W[64,64]) * dis.
// All 64 channels staged once into Xs[128][65] (relu fused in unpack), ONE
// barrier, one 64-deep K loop. Staging: thread (srow = t>>1, half = t&1)
// loads 16 uints (uints 16h..16h+15 = channels 32h..32h+31) — full row
// covered by the two threads (fixes R11's 8-uint/16-channel staging bug).
__global__ __launch_bounds__(256) void gemm2_kernel(const uint* __restrict__ X,
                                                    const float* __restrict__ W,
                                                    const float* __restrict__ dis,
                                                    uint* __restrict__ Y) {
    __shared__ float Wl[HID * 64];       // 16 KB
    __shared__ float Xs[128 * 65];       // 33.3 KB
    int t = threadIdx.x;
    for (int idx = t; idx < HID * 64; idx += 256) Wl[idx] = W[idx];

    int r0 = (t >> 3) * 4;
    int c0 = (t & 7) * 8;
    int rowBase = blockIdx.x * 128;

    {   // stage: thread (srow, half) unpacks uints 16h..16h+15 -> ch 32h..32h+31
        int srow = t >> 1, half = t & 1;
        bool sok = (rowBase + srow) < N_NODES;
        float* xs = &Xs[srow * 65 + half * 32];
        if (sok) {
            const uint* xb = X + (size_t)(rowBase + srow) * 32 + half * 16;
            uint4 u0 = *reinterpret_cast<const uint4*>(xb);
            uint4 u1 = *reinterpret_cast<const uint4*>(xb + 4);
            uint4 u2 = *reinterpret_cast<const uint4*>(xb + 8);
            uint4 u3 = *reinterpret_cast<const uint4*>(xb + 12);
            uint us[16] = {u0.x, u0.y, u0.z, u0.w, u1.x, u1.y, u1.z, u1.w,
                           u2.x, u2.y, u2.z, u2.w, u3.x, u3.y, u3.z, u3.w};
#pragma unroll
            for (int j = 0; j < 16; ++j) {
                float2 f = ub2(us[j]);
                xs[2 * j]     = fmaxf(f.x, 0.f);
                xs[2 * j + 1] = fmaxf(f.y, 0.f);
            }
        } else {
#pragma unroll
            for (int j = 0; j < 32; ++j) xs[j] = 0.f;
        }
    }
    __syncthreads();

    float acc[4][8];
#pragma unroll
    for (int a = 0; a < 4; ++a)
#pragma unroll
        for (int c = 0; c < 8; ++c) acc[a][c] = 0.f;

#pragma unroll 4
    for (int kk = 0; kk < HID; ++kk) {
        const float4 wa = *reinterpret_cast<const float4*>(&Wl[kk * 64 + c0]);
        const float4 wb = *reinterpret_cast<const float4*>(&Wl[kk * 64 + c0 + 4]);
        float xr[4];
#pragma unroll
        for (int a = 0; a < 4; ++a) xr[a] = Xs[(r0 + a) * 65 + kk];
#pragma unroll
        for (int a = 0; a < 4; ++a) {
            acc[a][0] += xr[a] * wa.x; acc[a][1] += xr[a] * wa.y;
            acc[a][2] += xr[a] * wa.z; acc[a][3] += xr[a] * wa.w;
            acc[a][4] += xr[a] * wb.x; acc[a][5] += xr[a] * wb.y;
            acc[a][6] += xr[a] * wb.z; acc[a][7] += xr[a] * wb.w;
        }
    }
#pragma unroll
    for (int a = 0; a < 4; ++a) {
        int row = rowBase + r0 + a;
        if (row < N_NODES) {
            float d = dis[row];
            uint4 o;
            o.x = pack2(acc[a][0] * d, acc[a][1] * d);
            o.y = pack2(acc[a][2] * d, acc[a][3] * d);
            o.z = pack2(acc[a][4] * d, acc[a][5] * d);
            o.w = pack2(acc[a][6] * d, acc[a][7] * d);
            *reinterpret_cast<uint4*>(Y + (size_t)row * 32 + (t & 7) * 4) = o;
        }
    }
}

// ---------------------------------------------------------------------------
// R0-proven gather: wave per node, 8 edges concurrent (8 lanes/edge, bf16x8 =
// 16B per lane), 16-edge unroll, f32x2 packed accumulation (v_pk_add_f32):
// B[i] = bf16(bias + dis[i] * (A[i] + sum A[src])),  A = (X@W)*dis  (bf16)
__global__ __launch_bounds__(256) void gather_kernel(const int* __restrict__ rstart,
                                                     const int* __restrict__ rend,
                                                     const int* __restrict__ csr_src,
                                                     const float* __restrict__ dis,
                                                     const float* __restrict__ bias,
                                                     const uint* __restrict__ A,
                                                     uint* __restrict__ B) {
    int i = blockIdx.x * 4 + (threadIdx.x >> 6);
    if (i >= N_NODES) return;
    int lane = threadIdx.x & 63;
    int q = lane >> 3;               // which of 8 concurrent edges
    int cu = (lane & 7) * 4;         // uint4 offset in 32-uint row (8 channels)

    float4 bi0 = *reinterpret_cast<const float4*>(&bias[(lane & 7) * 8]);
    float4 bi1 = *reinterpret_cast<const float4*>(&bias[(lane & 7) * 8 + 4]);

    int e = rstart[i];
    int end = rend[i];

    f32x2 a[4], b[4];
#pragma unroll
    for (int j = 0; j < 4; ++j) { a[j] = (f32x2)0.f; b[j] = (f32x2)0.f; }

    if (q == 0) {                    // self term (already *dis[i])
        uint4 u = *reinterpret_cast<const uint4*>(&A[(size_t)i * 32 + cu]);
        a[0] += up2(u.x); a[1] += up2(u.y); a[2] += up2(u.z); a[3] += up2(u.w);
    }
    for (; e + 16 <= end; e += 16) {
        int s0 = csr_src[e + q];
        int s1 = csr_src[e + 8 + q];
        uint4 u0 = *reinterpret_cast<const uint4*>(&A[(size_t)s0 * 32 + cu]);
        uint4 u1 = *reinterpret_cast<const uint4*>(&A[(size_t)s1 * 32 + cu]);
        a[0] += up2(u0.x); a[1] += up2(u0.y); a[2] += up2(u0.z); a[3] += up2(u0.w);
        b[0] += up2(u1.x); b[1] += up2(u1.y); b[2] += up2(u1.z); b[3] += up2(u1.w);
    }
    for (; e + 8 <= end; e += 8) {
        int s = csr_src[e + q];
        uint4 u = *reinterpret_cast<const uint4*>(&A[(size_t)s * 32 + cu]);
        a[0] += up2(u.x); a[1] += up2(u.y); a[2] += up2(u.z); a[3] += up2(u.w);
    }
    if (e + q < end) {
        int s = csr_src[e + q];
        uint4 u = *reinterpret_cast<const uint4*>(&A[(size_t)s * 32 + cu]);
        b[0] += up2(u.x); b[1] += up2(u.y); b[2] += up2(u.z); b[3] += up2(u.w);
    }
    float r[8];
#pragma unroll
    for (int j = 0; j < 4; ++j) {
        f32x2 s = a[j] + b[j];
        r[2 * j] = s.x; r[2 * j + 1] = s.y;
    }
#pragma unroll
    for (int j = 0; j < 8; ++j) {
        r[j] += __shfl_xor(r[j], 8);
        r[j] += __shfl_xor(r[j], 16);
        r[j] += __shfl_xor(r[j], 32);
    }
    if (q == 0) {
        float d = dis[i];
        uint4 o;
        o.x = pack2(bi0.x + d * r[0], bi0.y + d * r[1]);
        o.y = pack2(bi0.z + d * r[2], bi0.w + d * r[3]);
        o.z = pack2(bi1.x + d * r[4], bi1.y + d * r[5]);
        o.w = pack2(bi1.z + d * r[6], bi1.w + d * r[7]);
        *reinterpret_cast<uint4*>(B + (size_t)i * 32 + (lane & 7) * 4) = o;
    }
}

// ---------------------------------------------------------------------------
// Atomic-free pool + finalize (R10-proven): one block per graph; binary-search
// node range; 8 half-waves stride rows; LDS tree-reduce; direct store.
__global__ __launch_bounds__(256) void pool_final_kernel(const uint* __restrict__ B,
                                                         const int* __restrict__ batch,
                                                         float* __restrict__ out) {
    __shared__ float part[8][64];       // per-half-wave partials (2 KB)
    int g = blockIdx.x;
    int t = threadIdx.x;
    int hw = t >> 5;                    // half-wave 0..7
    int l = t & 31;                     // uint column (channels 2l, 2l+1)

    // lower_bound(batch, g) and lower_bound(batch, g+1) — uniform branches
    int a = 0, b = N_NODES;
    while (a < b) { int m = (a + b) >> 1; if (batch[m] < g) a = m + 1; else b = m; }
    int lo = a;
    b = N_NODES;
    while (a < b) { int m = (a + b) >> 1; if (batch[m] < g + 1) a = m + 1; else b = m; }
    int hi = a;

    float a0 = 0.f, a1 = 0.f;
    for (int n = lo + hw; n < hi; n += 8) {
        float2 f = ub2(B[(size_t)n * 32 + l]);
        a0 += fmaxf(f.x, 0.f);
        a1 += fmaxf(f.y, 0.f);
    }
    part[hw][2 * l] = a0;
    part[hw][2 * l + 1] = a1;
    __syncthreads();

    if (t < 64) {
        float s = 0.f;
#pragma unroll
        for (int j = 0; j < 8; ++j) s += part[j][t];
        out[g * 64 + t] = s / fmaxf((float)(hi - lo), 1.0f);
    }
}

// ---------------------------------------------------------------------------
extern "C" void kernel_launch(void* const* d_in, const int* in_sizes, int n_in,
                              void* d_out, int out_size, void* d_ws, size_t ws_size,
                              hipStream_t stream) {
    const float* x     = (const float*)d_in[0];
    const int*   edge  = (const int*)d_in[1];   // [2, E]: row0 = src, row1 = dst
    const int*   batch = (const int*)d_in[2];
    const float* W1    = (const float*)d_in[3];
    const float* b1    = (const float*)d_in[4];
    const float* W2    = (const float*)d_in[5];
    const float* b2    = (const float*)d_in[6];
    float* out = (float*)d_out;

    // workspace layout (elements)
    uint*  A        = (uint*)d_ws;                        // 3,200,000 u (bf16, ping)
    uint*  B        = A + (size_t)N_NODES * 32;           // 3,200,000 u (bf16, pong)
    uint*  pairs    = B + (size_t)N_NODES * 32;           // NB*CAP = 4,003,840 u
    int*   csr_src  = (int*)(pairs + (size_t)NB * CAP);   // NB*CAP = 4,003,840 i
    float* dis      = (float*)(csr_src + (size_t)NB * CAP); // 100,000 f
    int*   rstart   = (int*)(dis + N_NODES);              // 100,000 i
    int*   rend     = rstart + N_NODES;                   // 100,000 i
    int*   bcnt     = rend + N_NODES;                     // NB*16 = 6,256 i (padded)
    // total ~59 MB

    const int* src = edge;
    const int* dst = edge + N_EDGES;

    // zero bucket counters only
    hipMemsetAsync(bcnt, 0, NB * 16 * sizeof(int), stream);

    // CSR build: coalesced multisplit + per-bucket local fill
    scatter_kernel<<<NBLK, 256, 0, stream>>>(src, dst, bcnt, pairs);
    bucket_csr_kernel<<<NB, 512, 0, stream>>>(pairs, bcnt, csr_src, rstart, rend, dis);

    // layer 1: A = bf16((x@W1)*dis) ; B = bf16(b1 + dis*(A[i] + sum A[src]))
    gemm1_kernel<<<(N_NODES + 127) / 128, 256, 0, stream>>>(x, W1, dis, A);
    gather_kernel<<<(N_NODES + 3) / 4, 256, 0, stream>>>(rstart, rend, csr_src, dis, b1, A, B);

    // layer 2 (relu fused into single-stage GEMM2)
    gemm2_kernel<<<(N_NODES + 127) / 128, 256, 0, stream>>>(B, W2, dis, A);
    gather_kernel<<<(N_NODES + 3) / 4, 256, 0, stream>>>(rstart, rend, csr_src, dis, b2, A, B);

    // atomic-free pool + finalize (one block per graph, direct store)
    pool_final_kernel<<<N_GRAPHS, 256, 0, stream>>>(B, batch, out);
}